// Round 1
// baseline (292.914 us; speedup 1.0000x reference)
//
#include <hip/hip_runtime.h>
#include <stdint.h>

// Fused e3nn-style kernel builder for RS=[(16,0),(16,1)], N_DIM=64, N_PATH=1536.
// 16 points per 256-thread workgroup; 1024 workgroups.
// Phase 0: radii, h=silu(rad*W1+b1) -> LDS; per-point SH/CG/norm coefs -> LDS.
// Phase 1: fp32 VALU GEMM R = h@W2+b2 (thread: 6 paths x 16 points) -> LDS (bf16).
// Phase 2: assemble 64x64 kernel blocks, coalesced float4 stores.

#define PPW   16
#define NPATH 1536
#define HSTR  68    // h row stride (floats), pad vs 64
#define RSTR  1552  // R row stride (ushorts), 1536+16 to break bank alignment
#define CSTR  36    // coef row stride

__device__ __forceinline__ unsigned short f2bf(float f) {
    union { float f; uint32_t u; } v; v.f = f;
    return (unsigned short)((v.u + 0x7FFFu + ((v.u >> 16) & 1u)) >> 16);
}
__device__ __forceinline__ float bf2f(unsigned short s) {
    union { float f; uint32_t u; } v; v.u = ((uint32_t)s) << 16;
    return v.f;
}

__global__ __launch_bounds__(256, 2)
void qm9_fused(const float* __restrict__ rin, const float* __restrict__ W1,
               const float* __restrict__ b1, const float* __restrict__ W2,
               const float* __restrict__ b2, float* __restrict__ out)
{
    __shared__ float          h_lds[PPW][HSTR];
    __shared__ unsigned short R_lds[PPW][RSTR];
    __shared__ float          coef[PPW][CSTR];

    const int t  = threadIdx.x;
    const int wg = blockIdx.x;
    const int p  = t >> 4;   // point slot within WG
    const int g  = t & 15;   // column-group / k-chunk
    const int pt = wg * PPW + p;

    // ---------------- phase 0: h and per-point coefficients ----------------
    {
        const float x = rin[3*pt+0], y = rin[3*pt+1], z = rin[3*pt+2];
        const float r2  = x*x + y*y + z*z;
        const float rad = sqrtf(r2);
        #pragma unroll
        for (int d = 0; d < 4; ++d) {
            const int k = 4*g + d;
            const float pre = rad * W1[k] + b1[k];
            h_lds[p][k] = pre / (1.0f + expf(-pre));   // silu
        }
    }
    if (t < PPW) {
        const int pp = wg * PPW + t;
        const float x = rin[3*pp+0], y = rin[3*pp+1], z = rin[3*pp+2];
        const float r2   = x*x + y*y + z*z;
        const float inv  = rsqrtf(r2);
        const float inv2 = 1.0f / r2;
        const float c0  = 0.28209479177387814f;   // 0.5/sqrt(pi)
        const float c1  = 0.48860251190291992f;   // sqrt(3/(4pi))
        const float c2  = 1.09254843059207907f;   // sqrt(15/(4pi))
        const float c20 = 0.31539156525252005f;   // sqrt(5/(16pi))
        const float Y1 = c1*y*inv, Y2 = c1*z*inv, Y3 = c1*x*inv;
        const float Y4 = c2*x*y*inv2, Y5 = c2*y*z*inv2;
        const float Y6 = c20*(3.0f*z*z - r2)*inv2;
        const float Y7 = c2*x*z*inv2;
        const float Y8 = 0.5f*c2*(x*x - y*y)*inv2;
        const bool z0 = (r2 == 0.0f);
        const float n00 = z0 ? 0.88622692545275801f : 0.62665706865775012f; // sqrt(4pi)/{4, sqrt32}
        const float n01 = z0 ? 1.53499006295944860f : 1.08540188766074740f; // sqrt(12pi)/{4, sqrt32}
        const float n10 = z0 ? 0.88622692545275801f : 0.44311346272637900f; // sqrt(4pi)/{4, 8}
        const float n11 = z0 ? 1.53499006295944860f : 0.76749503147972430f; // sqrt(12pi)/{4, 8}
        const float SQ3I  = 0.57735026918962584f;
        const float SQ6I  = 0.40824829046386302f;
        const float SQ10I = 0.31622776601683794f;
        const float SQ30I = 0.18257418583505536f;
        float* cf = &coef[t][0];
        cf[0] = c0 * n00;                 // s00 (block 00)
        cf[1] = SQ3I * n01 * Y1;          // a_j (block 01), j in (y,z,x)
        cf[2] = SQ3I * n01 * Y2;
        cf[3] = SQ3I * n01 * Y3;
        cf[4] = SQ3I * n10 * Y1;          // b_i (block 10)
        cf[5] = SQ3I * n10 * Y2;
        cf[6] = SQ3I * n10 * Y3;
        // W11[i][j][l] = n11 * T_l[i,j], stored at 7 + (i*3+j)*3 + l
        const float d0 = SQ3I * c0 * n11;     // l=0: delta_ij/sqrt3 * Y0
        const float e  = SQ6I * n11;          // l=1: eps_ijk/sqrt6 * Y[1+k]
        cf[7+ 0]=d0;   cf[7+ 1]=0.0f;    cf[7+ 2]=n11*(-SQ30I*Y6 - SQ10I*Y8); // (0,0)
        cf[7+ 3]=0.0f; cf[7+ 4]= e*Y3;   cf[7+ 5]=n11*( SQ10I*Y5);            // (0,1)
        cf[7+ 6]=0.0f; cf[7+ 7]=-e*Y2;   cf[7+ 8]=n11*( SQ10I*Y4);            // (0,2)
        cf[7+ 9]=0.0f; cf[7+10]=-e*Y3;   cf[7+11]=n11*( SQ10I*Y5);            // (1,0)
        cf[7+12]=d0;   cf[7+13]=0.0f;    cf[7+14]=n11*( 2.0f*SQ30I*Y6);       // (1,1)
        cf[7+15]=0.0f; cf[7+16]= e*Y1;   cf[7+17]=n11*( SQ10I*Y7);            // (1,2)
        cf[7+18]=0.0f; cf[7+19]= e*Y2;   cf[7+20]=n11*( SQ10I*Y4);            // (2,0)
        cf[7+21]=0.0f; cf[7+22]=-e*Y1;   cf[7+23]=n11*( SQ10I*Y7);            // (2,1)
        cf[7+24]=d0;   cf[7+25]=0.0f;    cf[7+26]=n11*(-SQ30I*Y6 + SQ10I*Y8); // (2,2)
    }
    __syncthreads();

    // ---------------- phase 1: radial GEMM R = h @ W2 + b2 ----------------
    {
        float acc[6][16];
        #pragma unroll
        for (int c = 0; c < 6; ++c) {
            const float bb = b2[t + 256*c];
            #pragma unroll
            for (int q = 0; q < 16; ++q) acc[c][q] = bb;
        }
        for (int k0 = 0; k0 < 64; k0 += 4) {
            float hk[16][4];
            #pragma unroll
            for (int q = 0; q < 16; ++q) {
                const float4 hv = *(const float4*)&h_lds[q][k0];
                hk[q][0]=hv.x; hk[q][1]=hv.y; hk[q][2]=hv.z; hk[q][3]=hv.w;
            }
            float w[4][6];
            #pragma unroll
            for (int d = 0; d < 4; ++d) {
                const float* wr = W2 + (size_t)(k0+d)*NPATH + t;
                #pragma unroll
                for (int c = 0; c < 6; ++c) w[d][c] = wr[256*c];
            }
            #pragma unroll
            for (int c = 0; c < 6; ++c) {
                #pragma unroll
                for (int q = 0; q < 16; ++q) {
                    float s = acc[c][q];
                    #pragma unroll
                    for (int d = 0; d < 4; ++d) s += hk[q][d] * w[d][c];
                    acc[c][q] = s;
                }
            }
        }
        #pragma unroll
        for (int c = 0; c < 6; ++c)
            #pragma unroll
            for (int q = 0; q < 16; ++q)
                R_lds[q][t + 256*c] = f2bf(acc[c][q]);
    }
    __syncthreads();

    // ---------------- phase 2: assemble kernel, coalesced stores ----------------
    {
        const float* cf = &coef[p][0];
        const float s00 = cf[0];
        const float bI[3] = {cf[4], cf[5], cf[6]};
        int vq[4], jq[4], mq[4];
        float aj[4];
        const int cc0 = 4*g - 16;
        const int v0  = (g >= 4) ? (cc0 / 3) : 0;
        #pragma unroll
        for (int d = 0; d < 4; ++d) {
            const int cc = (g >= 4) ? (cc0 + d) : 0;
            vq[d] = cc / 3;
            jq[d] = cc - 3*vq[d];
            mq[d] = (vq[d] != v0);
            aj[d] = cf[1 + jq[d]];
        }
        float Wd[4][3][3];
        if (g >= 4) {
            #pragma unroll
            for (int d = 0; d < 4; ++d)
                #pragma unroll
                for (int i = 0; i < 3; ++i)
                    #pragma unroll
                    for (int l = 0; l < 3; ++l)
                        Wd[d][i][l] = cf[7 + (i*3 + jq[d])*3 + l];
        }
        const unsigned short* Rp = &R_lds[p][0];
        float* outp = out + (size_t)pt * 4096 + 4*g;

        // rows 0..15 (lo=0): cols<16 -> s00*R00; cols>=16 -> a_j*R01
        for (int u = 0; u < 16; ++u) {
            float v[4];
            if (g < 4) {
                const ushort4 rv = *(const ushort4*)&Rp[u*16 + 4*g];
                v[0]=s00*bf2f(rv.x); v[1]=s00*bf2f(rv.y);
                v[2]=s00*bf2f(rv.z); v[3]=s00*bf2f(rv.w);
            } else {
                #pragma unroll
                for (int d = 0; d < 4; ++d)
                    v[d] = aj[d] * bf2f(Rp[256 + u*16 + vq[d]]);
            }
            *(float4*)(outp + (size_t)u*64) = make_float4(v[0],v[1],v[2],v[3]);
        }
        // rows 16..63 (lo=1): cols<16 -> b_i*R10; cols>=16 -> sum_l W11*R11
        for (int u = 0; u < 16; ++u) {
            float rA[4];
            float rsel[4][3];
            if (g < 4) {
                const ushort4 rv = *(const ushort4*)&Rp[512 + u*16 + 4*g];
                rA[0]=bf2f(rv.x); rA[1]=bf2f(rv.y); rA[2]=bf2f(rv.z); rA[3]=bf2f(rv.w);
            } else {
                float rB[2][3];
                const int base = 768 + (u*16 + v0)*3;
                #pragma unroll
                for (int w2 = 0; w2 < 2; ++w2)
                    #pragma unroll
                    for (int l = 0; l < 3; ++l)
                        rB[w2][l] = bf2f(Rp[base + 3*w2 + l]);
                #pragma unroll
                for (int d = 0; d < 4; ++d)
                    #pragma unroll
                    for (int l = 0; l < 3; ++l)
                        rsel[d][l] = mq[d] ? rB[1][l] : rB[0][l];
            }
            #pragma unroll
            for (int i = 0; i < 3; ++i) {
                float v[4];
                if (g < 4) {
                    #pragma unroll
                    for (int d = 0; d < 4; ++d) v[d] = bI[i] * rA[d];
                } else {
                    #pragma unroll
                    for (int d = 0; d < 4; ++d)
                        v[d] = Wd[d][i][0]*rsel[d][0] + Wd[d][i][1]*rsel[d][1]
                             + Wd[d][i][2]*rsel[d][2];
                }
                *(float4*)(outp + (size_t)(16 + 3*u + i)*64) = make_float4(v[0],v[1],v[2],v[3]);
            }
        }
    }
}

extern "C" void kernel_launch(void* const* d_in, const int* in_sizes, int n_in,
                              void* d_out, int out_size, void* d_ws, size_t ws_size,
                              hipStream_t stream) {
    const float* r  = (const float*)d_in[0];
    const float* W1 = (const float*)d_in[1];
    const float* b1 = (const float*)d_in[2];
    const float* W2 = (const float*)d_in[3];
    const float* b2 = (const float*)d_in[4];
    float* out = (float*)d_out;
    qm9_fused<<<dim3(1024), dim3(256), 0, stream>>>(r, W1, b1, W2, b2, out);
}

// Round 2
// 283.486 us; speedup vs baseline: 1.0333x; 1.0333x over previous
//
#include <hip/hip_runtime.h>
#include <stdint.h>

// Fused e3nn-style kernel builder for RS=[(16,0),(16,1)], N_DIM=64, N_PATH=1536.
// Round 2: MFMA bf16 GEMM for R = h@W2+b2.
//   prep kernel: W2 (fp32 [k][n]) -> W2T (bf16 [n][k]) in d_ws.
//   main kernel: 16 points/WG, 1024 WGs, 3 WG/CU.
//     phase 0: per-lane A-fragments (h in bf16) computed in registers; coefs -> LDS.
//     phase 1: 96 N-tiles of mfma_f32_16x16x32_bf16 -> R_lds (bf16).
//     phase 2: assemble 64x64 kernel blocks, coalesced float4 stores (unchanged).

#define PPW   16
#define NPATH 1536
#define RSTR  1540  // R row stride (ushorts)
#define CSTR  34    // coef row stride (floats)

typedef __attribute__((ext_vector_type(8))) short short8;
typedef __attribute__((ext_vector_type(4))) float float4v;

__device__ __forceinline__ unsigned short f2bf(float f) {
    union { float f; uint32_t u; } v; v.f = f;
    return (unsigned short)((v.u + 0x7FFFu + ((v.u >> 16) & 1u)) >> 16);
}
__device__ __forceinline__ float bf2f(unsigned short s) {
    union { float f; uint32_t u; } v; v.u = ((uint32_t)s) << 16;
    return v.f;
}

// ---- prep: W2T[n*64+k] = bf16(W2[k*1536+n]) ----
__global__ void w2_prep(const float* __restrict__ W2, unsigned short* __restrict__ W2T) {
    const int idx = blockIdx.x * 256 + threadIdx.x;
    if (idx < 64 * NPATH) {
        const int n = idx >> 6, k = idx & 63;
        W2T[idx] = f2bf(W2[(size_t)k * NPATH + n]);
    }
}

__global__ __launch_bounds__(256, 3)
void qm9_fused(const float* __restrict__ rin, const float* __restrict__ W1,
               const float* __restrict__ b1, const unsigned short* __restrict__ W2T,
               const float* __restrict__ b2, float* __restrict__ out)
{
    __shared__ unsigned short R_lds[PPW][RSTR];
    __shared__ float          coef[PPW][CSTR];

    const int t  = threadIdx.x;
    const int wg = blockIdx.x;
    const int p  = t >> 4;          // point slot (phase 2)
    const int g  = t & 15;          // column-group (phase 2)
    const int pt = wg * PPW + p;
    const int wave = t >> 6;
    const int m  = t & 15;          // MFMA: row (point) = lane&15
    const int q  = (t >> 4) & 3;    // MFMA: quad = lane>>4

    // ---------------- phase 0a: A-fragments (h as bf16) in registers ----------------
    short8 afrag[2];
    {
        const int ptm = wg * PPW + m;
        const float x = rin[3*ptm+0], y = rin[3*ptm+1], z = rin[3*ptm+2];
        const float rad = sqrtf(x*x + y*y + z*z);
        #pragma unroll
        for (int kb = 0; kb < 2; ++kb) {
            const int k0 = kb*32 + q*8;
            const float4 w1a = *(const float4*)&W1[k0];
            const float4 w1b = *(const float4*)&W1[k0+4];
            const float4 b1a = *(const float4*)&b1[k0];
            const float4 b1b = *(const float4*)&b1[k0+4];
            float pre[8];
            pre[0]=rad*w1a.x+b1a.x; pre[1]=rad*w1a.y+b1a.y;
            pre[2]=rad*w1a.z+b1a.z; pre[3]=rad*w1a.w+b1a.w;
            pre[4]=rad*w1b.x+b1b.x; pre[5]=rad*w1b.y+b1b.y;
            pre[6]=rad*w1b.z+b1b.z; pre[7]=rad*w1b.w+b1b.w;
            #pragma unroll
            for (int j = 0; j < 8; ++j) {
                const float hv = pre[j] / (1.0f + expf(-pre[j]));
                afrag[kb][j] = (short)f2bf(hv);
            }
        }
    }

    // ---------------- phase 0b: per-point SH/CG/norm coefficients ----------------
    if (t < PPW) {
        const int pp = wg * PPW + t;
        const float x = rin[3*pp+0], y = rin[3*pp+1], z = rin[3*pp+2];
        const float r2   = x*x + y*y + z*z;
        const float inv  = rsqrtf(r2);
        const float inv2 = 1.0f / r2;
        const float c0  = 0.28209479177387814f;
        const float c1  = 0.48860251190291992f;
        const float c2  = 1.09254843059207907f;
        const float c20 = 0.31539156525252005f;
        const float Y1 = c1*y*inv, Y2 = c1*z*inv, Y3 = c1*x*inv;
        const float Y4 = c2*x*y*inv2, Y5 = c2*y*z*inv2;
        const float Y6 = c20*(3.0f*z*z - r2)*inv2;
        const float Y7 = c2*x*z*inv2;
        const float Y8 = 0.5f*c2*(x*x - y*y)*inv2;
        const bool z0 = (r2 == 0.0f);
        const float n00 = z0 ? 0.88622692545275801f : 0.62665706865775012f;
        const float n01 = z0 ? 1.53499006295944860f : 1.08540188766074740f;
        const float n10 = z0 ? 0.88622692545275801f : 0.44311346272637900f;
        const float n11 = z0 ? 1.53499006295944860f : 0.76749503147972430f;
        const float SQ3I  = 0.57735026918962584f;
        const float SQ6I  = 0.40824829046386302f;
        const float SQ10I = 0.31622776601683794f;
        const float SQ30I = 0.18257418583505536f;
        float* cf = &coef[t][0];
        cf[0] = c0 * n00;
        cf[1] = SQ3I * n01 * Y1;
        cf[2] = SQ3I * n01 * Y2;
        cf[3] = SQ3I * n01 * Y3;
        cf[4] = SQ3I * n10 * Y1;
        cf[5] = SQ3I * n10 * Y2;
        cf[6] = SQ3I * n10 * Y3;
        const float d0 = SQ3I * c0 * n11;
        const float e  = SQ6I * n11;
        cf[7+ 0]=d0;   cf[7+ 1]=0.0f;    cf[7+ 2]=n11*(-SQ30I*Y6 - SQ10I*Y8);
        cf[7+ 3]=0.0f; cf[7+ 4]= e*Y3;   cf[7+ 5]=n11*( SQ10I*Y5);
        cf[7+ 6]=0.0f; cf[7+ 7]=-e*Y2;   cf[7+ 8]=n11*( SQ10I*Y4);
        cf[7+ 9]=0.0f; cf[7+10]=-e*Y3;   cf[7+11]=n11*( SQ10I*Y5);
        cf[7+12]=d0;   cf[7+13]=0.0f;    cf[7+14]=n11*( 2.0f*SQ30I*Y6);
        cf[7+15]=0.0f; cf[7+16]= e*Y1;   cf[7+17]=n11*( SQ10I*Y7);
        cf[7+18]=0.0f; cf[7+19]= e*Y2;   cf[7+20]=n11*( SQ10I*Y4);
        cf[7+21]=0.0f; cf[7+22]=-e*Y1;   cf[7+23]=n11*( SQ10I*Y7);
        cf[7+24]=d0;   cf[7+25]=0.0f;    cf[7+26]=n11*(-SQ30I*Y6 + SQ10I*Y8);
    }

    // ---------------- phase 1: MFMA GEMM R = h @ W2 + b2 -> R_lds ----------------
    {
        for (int i = wave; i < 96; i += 4) {
            const int n0  = i * 16;
            const int col = n0 + m;
            const short8 b0 = *(const short8*)(W2T + (size_t)col*64 + q*8);
            const short8 b1f = *(const short8*)(W2T + (size_t)col*64 + 32 + q*8);
            float4v acc = {0.0f, 0.0f, 0.0f, 0.0f};
            acc = __builtin_amdgcn_mfma_f32_16x16x32_bf16(afrag[0], b0,  acc, 0, 0, 0);
            acc = __builtin_amdgcn_mfma_f32_16x16x32_bf16(afrag[1], b1f, acc, 0, 0, 0);
            const float bias = b2[col];
            #pragma unroll
            for (int r = 0; r < 4; ++r)
                R_lds[q*4 + r][col] = f2bf(acc[r] + bias);
        }
    }
    __syncthreads();

    // ---------------- phase 2: assemble kernel, coalesced stores ----------------
    {
        const float* cf = &coef[p][0];
        const float s00 = cf[0];
        const float bI[3] = {cf[4], cf[5], cf[6]};
        int vq[4], jq[4], mq[4];
        float aj[4];
        const int cc0 = 4*g - 16;
        const int v0  = (g >= 4) ? (cc0 / 3) : 0;
        #pragma unroll
        for (int d = 0; d < 4; ++d) {
            const int cc = (g >= 4) ? (cc0 + d) : 0;
            vq[d] = cc / 3;
            jq[d] = cc - 3*vq[d];
            mq[d] = (vq[d] != v0);
            aj[d] = cf[1 + jq[d]];
        }
        float Wd[4][3][3];
        if (g >= 4) {
            #pragma unroll
            for (int d = 0; d < 4; ++d)
                #pragma unroll
                for (int i = 0; i < 3; ++i)
                    #pragma unroll
                    for (int l = 0; l < 3; ++l)
                        Wd[d][i][l] = cf[7 + (i*3 + jq[d])*3 + l];
        }
        const unsigned short* Rp = &R_lds[p][0];
        float* outp = out + (size_t)pt * 4096 + 4*g;

        for (int u = 0; u < 16; ++u) {
            float v[4];
            if (g < 4) {
                const ushort4 rv = *(const ushort4*)&Rp[u*16 + 4*g];
                v[0]=s00*bf2f(rv.x); v[1]=s00*bf2f(rv.y);
                v[2]=s00*bf2f(rv.z); v[3]=s00*bf2f(rv.w);
            } else {
                #pragma unroll
                for (int d = 0; d < 4; ++d)
                    v[d] = aj[d] * bf2f(Rp[256 + u*16 + vq[d]]);
            }
            *(float4*)(outp + (size_t)u*64) = make_float4(v[0],v[1],v[2],v[3]);
        }
        for (int u = 0; u < 16; ++u) {
            float rA[4];
            float rsel[4][3];
            if (g < 4) {
                const ushort4 rv = *(const ushort4*)&Rp[512 + u*16 + 4*g];
                rA[0]=bf2f(rv.x); rA[1]=bf2f(rv.y); rA[2]=bf2f(rv.z); rA[3]=bf2f(rv.w);
            } else {
                float rB[2][3];
                const int base = 768 + (u*16 + v0)*3;
                #pragma unroll
                for (int w2 = 0; w2 < 2; ++w2)
                    #pragma unroll
                    for (int l = 0; l < 3; ++l)
                        rB[w2][l] = bf2f(Rp[base + 3*w2 + l]);
                #pragma unroll
                for (int d = 0; d < 4; ++d)
                    #pragma unroll
                    for (int l = 0; l < 3; ++l)
                        rsel[d][l] = mq[d] ? rB[1][l] : rB[0][l];
            }
            #pragma unroll
            for (int i = 0; i < 3; ++i) {
                float v[4];
                if (g < 4) {
                    #pragma unroll
                    for (int d = 0; d < 4; ++d) v[d] = bI[i] * rA[d];
                } else {
                    #pragma unroll
                    for (int d = 0; d < 4; ++d)
                        v[d] = Wd[d][i][0]*rsel[d][0] + Wd[d][i][1]*rsel[d][1]
                             + Wd[d][i][2]*rsel[d][2];
                }
                *(float4*)(outp + (size_t)(16 + 3*u + i)*64) = make_float4(v[0],v[1],v[2],v[3]);
            }
        }
    }
}

extern "C" void kernel_launch(void* const* d_in, const int* in_sizes, int n_in,
                              void* d_out, int out_size, void* d_ws, size_t ws_size,
                              hipStream_t stream) {
    const float* r  = (const float*)d_in[0];
    const float* W1 = (const float*)d_in[1];
    const float* b1 = (const float*)d_in[2];
    const float* W2 = (const float*)d_in[3];
    const float* b2 = (const float*)d_in[4];
    float* out = (float*)d_out;
    unsigned short* W2T = (unsigned short*)d_ws;

    w2_prep<<<dim3((64*NPATH + 255)/256), dim3(256), 0, stream>>>(W2, W2T);
    qm9_fused<<<dim3(1024), dim3(256), 0, stream>>>(r, W1, b1, W2T, b2, out);
}